// Round 9
// baseline (216.241 us; speedup 1.0000x reference)
//
#include <hip/hip_runtime.h>

// out[t][e] = (W[e][ids[t]] + b[e]) * sqrt(512)
// W: (512, 50257) row-major f32; ids: 32768 int32; out: 32768 x 512 f32.
//
// Round 13: read-run length 1 KB -> 2 KB + bucket-fast block order
// (DRAM activate-rate model: run length is the only lever that has ever
// moved effective BW; R12's 1 KB runs put scatter under the fills).
//  - VB=512: staged row segment = 2 KB contiguous (8 back-to-back 256 B
//    DMAs). NB=99 buckets, CAP=448 (mean 331, sigma 18).
//  - Block = (bucket b FAST, e-chunk ec of 32 rows SLOW): co-resident blocks
//    cover all buckets of ~5 adjacent e-chunks -> their 2 KB runs tile the
//    same DRAM pages (run merging at the controller).
//  - Tile 32 x 513 dwords (~65.7 KB dynamic LDS) -> 2 blocks/CU.
//    Pad dword/row: scatter read tile[el*513+vl] -> bank (el+vl)%32,
//    conflict-free per half-wave, 2-way across halves (free, m136).
//  - Scatter: 2 tokens/wave/iter (half-wave each): 1 ds_read + ONE 128 B
//    contiguous store. toks[] in LDS (uniform-ish broadcast read).
//  - memset for counts; overflow folded into b==0 blocks (16 ec-blocks).

constexpr int VOCAB = 50257;
constexpr int EMB   = 512;
constexpr int NTOK  = 8 * 4096;
constexpr float SCALE = 22.62741699796952f;  // sqrt(512)

constexpr int VB   = 512;                     // vocab ids per bucket
constexpr int NB   = (VOCAB + VB - 1) / VB;   // 99 buckets
constexpr int CAP  = 448;                     // capacity (mean 331, sigma 18)
constexpr int ECH  = 32;                      // e-rows per block
constexpr int NEC  = EMB / ECH;               // 16 e-chunks
constexpr int RSD  = VB + 1;                  // LDS row stride in dwords (513)
constexpr int SMEM_BYTES = (ECH * RSD + CAP) * 4;   // 67,456 B

// d_ws int layout: counts[NB] | ocount[1] | olist[NTOK] | buckets[NB*CAP]

__global__ __launch_bounds__(256) void build_buckets(
    const int* __restrict__ ids,
    int* __restrict__ counts,
    int* __restrict__ olist,
    int* __restrict__ buckets)
{
    int t = blockIdx.x * 256 + threadIdx.x;
    int id = ids[t];
    int bkt = id >> 9;
    int slot = atomicAdd(&counts[bkt], 1);
    if (slot < CAP) {
        buckets[bkt * CAP + slot] = (t << 9) | (id & 511);
    } else {
        int o = atomicAdd(&counts[NB], 1);
        olist[o] = t;
    }
}

__global__ __launch_bounds__(512) void scatter_main(
    const float* __restrict__ W,
    const float* __restrict__ bias,
    const int*   __restrict__ counts,
    const int*   __restrict__ buckets,
    const int*   __restrict__ olist,
    const int*   __restrict__ ids,
    float*       __restrict__ out)
{
    extern __shared__ float smem[];
    float* tile = smem;                        // 32 x 513 dwords
    int*   toks = (int*)(smem + ECH * RSD);    // 448 ints

    const int bid  = blockIdx.x;
    const int b    = bid % NB;            // bucket (FAST: page merging)
    const int ec   = bid / NB;            // e-chunk 0..15 (slow)
    const int e0   = ec * ECH;
    const int tid  = threadIdx.x;
    const int lane = tid & 63;
    const int w    = tid >> 6;            // wave id 0..7

    const int vstart = min(b * VB, VOCAB - VB);
    const int vadj   = b * VB - vstart;   // 0 except last bucket (431)

    const int cnt = min(counts[b], CAP);  // block-uniform scalar load
    if (tid < CAP) toks[tid] = buckets[b * CAP + tid];
    const int   el = lane & 31;
    const float be = bias[e0 + el];

    // ---- stage: wave w rows [w*4, w*4+4); 8 seq 256 B DMAs per row ----
    // Per-wave address stream: 2 KB contiguous runs, then a 201 KB jump.
    #pragma unroll
    for (int p = 0; p < 4; ++p) {
        const int r = w * 4 + p;
        const size_t rowbase = (size_t)(e0 + r) * VOCAB + vstart;
        #pragma unroll
        for (int q = 0; q < 8; ++q) {
            const float* gp = W + rowbase + q * 64 + lane;
            float* lp = &tile[r * RSD + q * 64];     // wave-uniform base
            __builtin_amdgcn_global_load_lds(
                (const __attribute__((address_space(1))) void*)gp,
                (__attribute__((address_space(3))) void*)lp, 4, 0, 0);
        }
    }
    __syncthreads();                      // DMA drained; tile + toks visible

    // ---- scatter: 2 tokens/wave/iter; 1 ds_read + 128 B store each ----
    const int h = lane >> 5;
    const float* tl   = &tile[el * RSD];
    float*       outp = out + e0 + el;
    for (int i = 2 * w + h; i < cnt; i += 16) {
        const int pk = toks[i];
        const int t  = pk >> 9;
        const int vl = (pk & 511) + vadj;
        outp[(size_t)t * EMB] = (tl[vl] + be) * SCALE;
    }

    // ---- overflow fix (expected n == 0): b==0 blocks, each its e-chunk ----
    if (b == 0) {
        int n = counts[NB];
        for (int ww = w; ww < n; ww += 8) {
            int t  = olist[ww];
            int id = ids[t];
            if (h == 0) {
                int e = e0 + el;
                out[(size_t)t * EMB + e] = (W[(size_t)e * VOCAB + id] + bias[e]) * SCALE;
            }
        }
    }
}

// Fallback (round-1 kernel) if d_ws is too small.
__global__ __launch_bounds__(256) void embed_gather(
    const int*   __restrict__ ids,
    const float* __restrict__ W,
    const float* __restrict__ b,
    float*       __restrict__ out)
{
    int idx4 = blockIdx.x * blockDim.x + threadIdx.x;
    int t    = idx4 >> 7;
    int e    = (idx4 & 127) << 2;
    int id = ids[t];
    float4 bb = *reinterpret_cast<const float4*>(b + e);
    const float* wcol = W + (size_t)id;
    float4 o;
    o.x = (wcol[(size_t)(e + 0) * VOCAB] + bb.x) * SCALE;
    o.y = (wcol[(size_t)(e + 1) * VOCAB] + bb.y) * SCALE;
    o.z = (wcol[(size_t)(e + 2) * VOCAB] + bb.z) * SCALE;
    o.w = (wcol[(size_t)(e + 3) * VOCAB] + bb.w) * SCALE;
    *reinterpret_cast<float4*>(out + (size_t)idx4 * 4) = o;
}

extern "C" void kernel_launch(void* const* d_in, const int* in_sizes, int n_in,
                              void* d_out, int out_size, void* d_ws, size_t ws_size,
                              hipStream_t stream)
{
    const int*   ids  = (const int*)  d_in[0];
    const float* W    = (const float*)d_in[1];
    const float* bias = (const float*)d_in[2];
    float*       out  = (float*)d_out;

    const size_t ws_ints_needed = (size_t)NB + 1 + NTOK + (size_t)NB * CAP;

    if (ws_size >= ws_ints_needed * sizeof(int)) {
        int* counts  = (int*)d_ws;
        int* olist   = counts + NB + 1;
        int* buckets = olist + NTOK;

        hipMemsetAsync(counts, 0, (NB + 1) * sizeof(int), stream);
        build_buckets<<<NTOK / 256, 256, 0, stream>>>(ids, counts, olist, buckets);
        scatter_main<<<NB * NEC, 512, SMEM_BYTES, stream>>>(W, bias, counts, buckets,
                                                            olist, ids, out);
    } else {
        constexpr int total4 = NTOK * EMB / 4;
        embed_gather<<<total4 / 256, 256, 0, stream>>>(ids, W, bias, out);
    }
}

// Round 10
// 190.496 us; speedup vs baseline: 1.1351x; 1.1351x over previous
//
#include <hip/hip_runtime.h>

// out[t][e] = (W[e][ids[t]] + b[e]) * sqrt(512)
// W: (512, 50257) row-major f32; ids: 32768 int32; out: 32768 x 512 f32.
//
// Round 14: single-burst 2 KB token writes (write-activate floor test).
// Evidence: WRITE=65.5 MB at 0.99-1.13 TB/s in ALL eleven configs while
// FETCH varied 55-100 MB and read-run 128B-2KB with zero duration effect
// => the 64 MB random-write permutation is the floor. Every prior config
// wrote each token row in >=2 temporally-separated 1 KB bursts.
//  - VB=32 (NB=1571): build back to 21 atomics/addr (R12/R13 regressed via
//    build contention, not scatter).
//  - Block = bucket x ALL 512 e-rows: tile 512 x 33 dwords (~68 KB dynamic
//    LDS, 2 blocks/CU, 512 threads/8 waves). Padded stride 33: staging
//    ds_writes conflict-free; scatter reads 8-way (negligible volume).
//  - Reg-staging, scalar f32 loads (no 16B-alignment constraints; proven
//    equivalent to DMA in R8).
//  - Scatter: one token per WAVE per iter: 8 ds_reads + TWO back-to-back
//    dwordx4 stores = one 2 KB contiguous burst; a token's row is written
//    ONCE, by one block, in one burst.

constexpr int VOCAB = 50257;
constexpr int EMB   = 512;
constexpr int NTOK  = 8 * 4096;
constexpr float SCALE = 22.62741699796952f;  // sqrt(512)

constexpr int VB   = 32;                      // vocab ids per bucket
constexpr int NB   = (VOCAB + VB - 1) / VB;   // 1571 buckets
constexpr int CAP  = 96;                      // capacity (mean 20.9, sigma 4.6)
constexpr int RS   = VB + 1;                  // LDS row stride in dwords (33)
constexpr int TILE_DW = EMB * RS;             // 16896 dwords
constexpr int SMEM_BYTES = (TILE_DW + CAP) * 4;   // 67,968 B

// d_ws int layout: counts[NB] | ocount[1] | olist[NTOK] | buckets[NB*CAP]

__global__ __launch_bounds__(256) void build_buckets(
    const int* __restrict__ ids,
    int* __restrict__ counts,
    int* __restrict__ olist,
    int* __restrict__ buckets)
{
    int t = blockIdx.x * 256 + threadIdx.x;
    int id = ids[t];
    int bkt = id >> 5;
    int slot = atomicAdd(&counts[bkt], 1);
    if (slot < CAP) {
        buckets[bkt * CAP + slot] = (t << 5) | (id & 31);
    } else {
        int o = atomicAdd(&counts[NB], 1);
        olist[o] = t;
    }
}

__global__ __launch_bounds__(512) void scatter_main(
    const float* __restrict__ W,
    const float* __restrict__ bias,
    const int*   __restrict__ counts,
    const int*   __restrict__ buckets,
    const int*   __restrict__ olist,
    const int*   __restrict__ ids,
    float*       __restrict__ out)
{
    extern __shared__ float smem[];
    float* tile = smem;                    // 512 rows x 33 dwords (padded)
    int*   toks = (int*)(smem + TILE_DW);  // 96 ints

    const int b    = blockIdx.x;          // bucket
    const int tid  = threadIdx.x;
    const int lane = tid & 63;
    const int w    = tid >> 6;            // wave id 0..7

    const int vstart = min(b * VB, VOCAB - VB);
    const int vadj   = b * VB - vstart;   // 0 except last bucket (15)

    const int cnt = min(counts[b], CAP);  // block-uniform scalar load
    if (tid < CAP) toks[tid] = buckets[b * CAP + tid];

    // Bias fragments for the two store halves: e = 4*lane+k and 256+4*lane+k.
    const float4 bA = reinterpret_cast<const float4*>(bias)[lane];
    const float4 bB = reinterpret_cast<const float4*>(bias)[64 + lane];

    // ---- reg-stage all 512 rows x 32 cols (scalar loads, any alignment) ----
    // Pass p covers rows [p*16, p*16+16): thread -> (row = p*16 + tid>>5,
    // col = tid&31). Consecutive lanes = consecutive addresses (128 B runs).
    const int rr  = tid >> 5;             // 0..15
    const int col = tid & 31;
    float v[32];
    #pragma unroll
    for (int p = 0; p < 32; ++p)
        v[p] = W[(size_t)(p * 16 + rr) * VOCAB + vstart + col];
    // Padded ds_writes: bank (row + col) % 32 -> conflict-free per half-wave.
    #pragma unroll
    for (int p = 0; p < 32; ++p)
        tile[(p * 16 + rr) * RS + col] = v[p];

    __syncthreads();                      // tile + toks visible

    // ---- scatter: one token per wave; ONE 2 KB contiguous burst ----
    float4* outv = reinterpret_cast<float4*>(out);
    for (int i = w; i < cnt; i += 8) {
        const int pk = toks[i];
        const int t  = pk >> 5;
        const int vl = (pk & 31) + vadj;
        float4 oA, oB;
        oA.x = tile[(4 * lane + 0) * RS + vl];
        oA.y = tile[(4 * lane + 1) * RS + vl];
        oA.z = tile[(4 * lane + 2) * RS + vl];
        oA.w = tile[(4 * lane + 3) * RS + vl];
        oB.x = tile[(256 + 4 * lane + 0) * RS + vl];
        oB.y = tile[(256 + 4 * lane + 1) * RS + vl];
        oB.z = tile[(256 + 4 * lane + 2) * RS + vl];
        oB.w = tile[(256 + 4 * lane + 3) * RS + vl];
        oA.x = (oA.x + bA.x) * SCALE;
        oA.y = (oA.y + bA.y) * SCALE;
        oA.z = (oA.z + bA.z) * SCALE;
        oA.w = (oA.w + bA.w) * SCALE;
        oB.x = (oB.x + bB.x) * SCALE;
        oB.y = (oB.y + bB.y) * SCALE;
        oB.z = (oB.z + bB.z) * SCALE;
        oB.w = (oB.w + bB.w) * SCALE;
        // Two back-to-back dwordx4 stores: wave covers [t*2048, t*2048+2048).
        outv[(size_t)t * 128 + lane]      = oA;
        outv[(size_t)t * 128 + 64 + lane] = oB;
    }

    // ---- overflow fix (expected n == 0): b==0 block handles olist ----
    if (b == 0) {
        int n = counts[NB];
        for (int ww = w; ww < n; ww += 8) {
            int t  = olist[ww];
            int id = ids[t];
            #pragma unroll
            for (int m = 0; m < 8; ++m) {
                int e = lane + m * 64;
                out[(size_t)t * EMB + e] = (W[(size_t)e * VOCAB + id] + bias[e]) * SCALE;
            }
        }
    }
}

// Fallback (round-1 kernel) if d_ws is too small.
__global__ __launch_bounds__(256) void embed_gather(
    const int*   __restrict__ ids,
    const float* __restrict__ W,
    const float* __restrict__ b,
    float*       __restrict__ out)
{
    int idx4 = blockIdx.x * blockDim.x + threadIdx.x;
    int t    = idx4 >> 7;
    int e    = (idx4 & 127) << 2;
    int id = ids[t];
    float4 bb = *reinterpret_cast<const float4*>(b + e);
    const float* wcol = W + (size_t)id;
    float4 o;
    o.x = (wcol[(size_t)(e + 0) * VOCAB] + bb.x) * SCALE;
    o.y = (wcol[(size_t)(e + 1) * VOCAB] + bb.y) * SCALE;
    o.z = (wcol[(size_t)(e + 2) * VOCAB] + bb.z) * SCALE;
    o.w = (wcol[(size_t)(e + 3) * VOCAB] + bb.w) * SCALE;
    *reinterpret_cast<float4*>(out + (size_t)idx4 * 4) = o;
}

extern "C" void kernel_launch(void* const* d_in, const int* in_sizes, int n_in,
                              void* d_out, int out_size, void* d_ws, size_t ws_size,
                              hipStream_t stream)
{
    const int*   ids  = (const int*)  d_in[0];
    const float* W    = (const float*)d_in[1];
    const float* bias = (const float*)d_in[2];
    float*       out  = (float*)d_out;

    const size_t ws_ints_needed = (size_t)NB + 1 + NTOK + (size_t)NB * CAP;

    if (ws_size >= ws_ints_needed * sizeof(int)) {
        int* counts  = (int*)d_ws;
        int* olist   = counts + NB + 1;
        int* buckets = olist + NTOK;

        hipMemsetAsync(counts, 0, (NB + 1) * sizeof(int), stream);
        build_buckets<<<NTOK / 256, 256, 0, stream>>>(ids, counts, olist, buckets);
        scatter_main<<<NB, 512, SMEM_BYTES, stream>>>(W, bias, counts, buckets,
                                                      olist, ids, out);
    } else {
        constexpr int total4 = NTOK * EMB / 4;
        embed_gather<<<total4 / 256, 256, 0, stream>>>(ids, W, bias, out);
    }
}